// Round 1
// baseline (13914.539 us; speedup 1.0000x reference)
//
#include <hip/hip_runtime.h>
#include <cstdint>

// Decoder (DA-RNN style): B=512, T=256, E=256, D=256.
// Strategy:
//  - Prep kernels: transpose w1_enc; convert input_encoded -> fp16; convert
//    w1_hc -> fp16; transpose W_hh -> fp16 [j][k]; GEMM enc_proj then store
//    P = exp(2*enc_proj) as fp16.
//  - Scan kernel: 256 workgroups x 512 threads, each wg owns 2 batch rows and
//    runs the entire 256-step scan using LDS state. tanh(a+q) computed as
//    1 - 2/(P*Q+1), Q = exp(2q) computed once per (b,e) per step.
// Workspace: ~129 MB (P_h 64MB, x_h 64MB, wT 256KB, w1hc_h 256KB, WhhT_h 512KB).

typedef _Float16 half8 __attribute__((ext_vector_type(8)));
typedef _Float16 half4v __attribute__((ext_vector_type(4)));

__device__ __forceinline__ float rcpf_(float x) { return __builtin_amdgcn_rcpf(x); }
__device__ __forceinline__ float sigmoidf_(float x) { return rcpf_(1.f + __expf(-x)); }
__device__ __forceinline__ float tanhf_(float x) { return 1.f - 2.f * rcpf_(1.f + __expf(2.f * x)); }

// wT[e*256+f] = attn_w1[f*768 + 512 + e]   (transposed w1_enc)
__global__ void k_prep_wT(const float* __restrict__ w1, float* __restrict__ wT) {
  int id = blockIdx.x * 256 + threadIdx.x;
  int e = id >> 8, f = id & 255;
  wT[id] = w1[f * 768 + 512 + e];
}

// x -> fp16 (4 elems/thread)
__global__ void k_prep_xh(const float* __restrict__ x, _Float16* __restrict__ xh) {
  int id = blockIdx.x * 256 + threadIdx.x;
  float4 v = reinterpret_cast<const float4*>(x)[id];
  half4v h;
  h[0] = (_Float16)v.x; h[1] = (_Float16)v.y; h[2] = (_Float16)v.z; h[3] = (_Float16)v.w;
  reinterpret_cast<half4v*>(xh)[id] = h;
}

// w1hc_h[e*512+j] = attn_w1[e*768 + j]
__global__ void k_prep_w1hc(const float* __restrict__ w1, _Float16* __restrict__ o) {
  int id = blockIdx.x * 256 + threadIdx.x;
  int e = id >> 9, j = id & 511;
  o[id] = (_Float16)w1[e * 768 + j];
}

// WhhT_h[j*1024 + k] = W_hh[k*256 + j]
__global__ void k_prep_whhT(const float* __restrict__ whh, _Float16* __restrict__ o) {
  int id = blockIdx.x * 256 + threadIdx.x;
  int j = id >> 10, k = id & 1023;
  o[id] = (_Float16)whh[k * 256 + j];
}

// enc_proj GEMM (131072 x 256 x 256) + bias, then P = exp(2*encp) stored fp16.
__global__ __launch_bounds__(256) void k_encp(const float* __restrict__ x,
                                              const float* __restrict__ wT,
                                              const float* __restrict__ b1,
                                              _Float16* __restrict__ Ph) {
  __shared__ __align__(16) float xl[16][256];
  const int tid = threadIdx.x;
  const int m0 = blockIdx.x * 16;
#pragma unroll
  for (int r = 0; r < 16; ++r) xl[r][tid] = x[(size_t)(m0 + r) * 256 + tid];
  __syncthreads();
  float acc[16];
#pragma unroll
  for (int r = 0; r < 16; ++r) acc[r] = 0.f;
  for (int e = 0; e < 256; e += 4) {
    float w0 = wT[(e + 0) * 256 + tid];
    float w1_ = wT[(e + 1) * 256 + tid];
    float w2_ = wT[(e + 2) * 256 + tid];
    float w3_ = wT[(e + 3) * 256 + tid];
#pragma unroll
    for (int r = 0; r < 16; ++r) {
      float4 xv = *reinterpret_cast<const float4*>(&xl[r][e]);
      acc[r] = fmaf(xv.x, w0, acc[r]);
      acc[r] = fmaf(xv.y, w1_, acc[r]);
      acc[r] = fmaf(xv.z, w2_, acc[r]);
      acc[r] = fmaf(xv.w, w3_, acc[r]);
    }
  }
  float bb = b1[tid];
#pragma unroll
  for (int r = 0; r < 16; ++r) {
    float p = __expf(2.f * (acc[r] + bb));
    Ph[(size_t)(m0 + r) * 256 + tid] = (_Float16)p;
  }
}

// The persistent scan: one wg (512 threads) per 2 batch rows, 256 steps.
__global__ __launch_bounds__(512, 2) void k_scan(
    const _Float16* __restrict__ Ph, const _Float16* __restrict__ xh,
    const _Float16* __restrict__ w1hc, const _Float16* __restrict__ whhT,
    const float* __restrict__ y_hist, const float* __restrict__ w2g,
    const float* __restrict__ Wih, const float* __restrict__ bih,
    const float* __restrict__ bhh, const float* __restrict__ fcw,
    const float* __restrict__ fcb, const float* __restrict__ fcfw,
    const float* __restrict__ fcfb, float* __restrict__ out) {
  __shared__ __align__(16) float hc[2][512];       // [g][ h(256) | c(256) ]
  __shared__ __align__(16) float ctxs[2][256];
  __shared__ __align__(16) float qpart[2][2][256]; // [g][jhalf][e]
  __shared__ __align__(16) float Qs[2][256];       // exp(2q)
  __shared__ __align__(16) float ealpha[2][256];   // unnormalized softmax
  __shared__ __align__(16) float cpart[2][8][256]; // ctx partials per t8 group
  __shared__ __align__(16) float gatesS[2][1024];
  __shared__ __align__(16) float w2l[256];
  __shared__ __align__(16) float Wihl[1024];
  __shared__ __align__(16) float bl[1024];
  __shared__ __align__(16) float fcwl[257];
  __shared__ float redA[8], redB[8];

  const int tid = threadIdx.x;
  const int g = tid >> 8;   // which of the 2 batch rows this thread's per-(g) work targets
  const int tt = tid & 255;
  const int wv = tid >> 6;  // wave 0..7 (waves 0-3 -> g=0, 4-7 -> g=1)
  const int lane = tid & 63;
  const int b0 = blockIdx.x * 2;

  // ---- init LDS ----
  ((float*)hc)[tid] = 0.f;
  ((float*)hc)[tid + 512] = 0.f;
  if (g == 0) w2l[tt] = w2g[tt];
  Wihl[tid] = Wih[tid];
  Wihl[tid + 512] = Wih[tid + 512];
  bl[tid] = bih[tid] + bhh[tid];
  bl[tid + 512] = bih[tid + 512] + bhh[tid + 512];
  if (tid < 257) fcwl[tid] = fcw[tid];
  __syncthreads();
  float w2sum = 0.f;
  for (int e2 = 0; e2 < 256; ++e2) w2sum += w2l[e2];
  const float fcb0 = fcb[0];
  const float fcwy = fcwl[256];

  const int eQ = tid >> 1, jh = tid & 1;
  const half8* wrowQ = reinterpret_cast<const half8*>(w1hc + eQ * 512 + jh * 256);
  const half8* prow = reinterpret_cast<const half8*>(Ph + ((size_t)(b0 + g) * 256 + tt) * 256);
  const int t8 = tt >> 5, l5 = tt & 31;
  const half8* xrow = reinterpret_cast<const half8*>(xh + ((size_t)(b0 + g) * 256 + t8 * 32) * 256);
  const unsigned int* wgr = reinterpret_cast<const unsigned int*>(whhT); // [j*512 + tid] = 2 halfs
  const float* yh0 = y_hist + (size_t)b0 * 256;
  const float* yh1 = y_hist + (size_t)(b0 + 1) * 256;

#pragma unroll 1
  for (int s = 0; s < 256; ++s) {
    // ---- q = hc @ w1_hc^T (both g), split over j-halves ----
    float a0 = 0.f, a1 = 0.f;
    {
      const float* hc0 = &hc[0][jh * 256];
      const float* hc1 = &hc[1][jh * 256];
#pragma unroll 8
      for (int c = 0; c < 32; ++c) {
        half8 wv8 = wrowQ[c];
#pragma unroll
        for (int m = 0; m < 8; ++m) {
          float w = (float)wv8[m];
          a0 = fmaf(w, hc0[c * 8 + m], a0);
          a1 = fmaf(w, hc1[c * 8 + m], a1);
        }
      }
    }
    qpart[0][jh][eQ] = a0;
    qpart[1][jh][eQ] = a1;
    __syncthreads(); // B1
    {
      float qv = qpart[g][0][tt] + qpart[g][1][tt];
      Qs[g][tt] = __expf(2.f * qv);
    }
    __syncthreads(); // B2

    // ---- scores: sc[tt] = sum_e w2[e]*tanh(encp+q) = w2sum - 2*sum w2[e]/(P*Q+1) ----
    float sacc = 0.f;
    {
      const float4* q4 = reinterpret_cast<const float4*>(&Qs[g][0]);
      const float4* w4 = reinterpret_cast<const float4*>(&w2l[0]);
#pragma unroll 8
      for (int c = 0; c < 32; ++c) {
        half8 pv = prow[c];
        float4 qa = q4[2 * c], qb = q4[2 * c + 1];
        float4 wa = w4[2 * c], wb = w4[2 * c + 1];
        sacc = fmaf(wa.x, rcpf_(fmaf((float)pv[0], qa.x, 1.f)), sacc);
        sacc = fmaf(wa.y, rcpf_(fmaf((float)pv[1], qa.y, 1.f)), sacc);
        sacc = fmaf(wa.z, rcpf_(fmaf((float)pv[2], qa.z, 1.f)), sacc);
        sacc = fmaf(wa.w, rcpf_(fmaf((float)pv[3], qa.w, 1.f)), sacc);
        sacc = fmaf(wb.x, rcpf_(fmaf((float)pv[4], qb.x, 1.f)), sacc);
        sacc = fmaf(wb.y, rcpf_(fmaf((float)pv[5], qb.y, 1.f)), sacc);
        sacc = fmaf(wb.z, rcpf_(fmaf((float)pv[6], qb.z, 1.f)), sacc);
        sacc = fmaf(wb.w, rcpf_(fmaf((float)pv[7], qb.w, 1.f)), sacc);
      }
    }
    float sc = w2sum - 2.f * sacc;

    // ---- softmax over t (per g: 4 waves) ----
    float mx = sc;
#pragma unroll
    for (int off = 32; off > 0; off >>= 1) mx = fmaxf(mx, __shfl_xor(mx, off));
    if (lane == 0) redA[wv] = mx;
    __syncthreads(); // B3
    float gm = fmaxf(fmaxf(redA[g * 4 + 0], redA[g * 4 + 1]),
                     fmaxf(redA[g * 4 + 2], redA[g * 4 + 3]));
    float ea = __expf(sc - gm);
    ealpha[g][tt] = ea;
    float es = ea;
#pragma unroll
    for (int off = 32; off > 0; off >>= 1) es += __shfl_xor(es, off);
    if (lane == 0) redB[wv] = es;
    __syncthreads(); // B4
    float ssum = redB[g * 4 + 0] + redB[g * 4 + 1] + redB[g * 4 + 2] + redB[g * 4 + 3];
    float rs = rcpf_(ssum);

    // ---- context = sum_t alpha[t] * x[t,:] (8 t-groups x 32 lanes x 8 e) ----
    float ac[8];
#pragma unroll
    for (int m = 0; m < 8; ++m) ac[m] = 0.f;
#pragma unroll 4
    for (int it = 0; it < 32; ++it) {
      float al = ealpha[g][t8 * 32 + it];
      half8 xv = xrow[it * 32 + l5];
#pragma unroll
      for (int m = 0; m < 8; ++m) ac[m] = fmaf(al, (float)xv[m], ac[m]);
    }
#pragma unroll
    for (int m = 0; m < 8; ++m) cpart[g][t8][l5 * 8 + m] = ac[m];
    __syncthreads(); // B5

    // ---- combine ctx, y_tilde partial ----
    float cv = 0.f;
#pragma unroll
    for (int u = 0; u < 8; ++u) cv += cpart[g][u][tt];
    cv *= rs;
    ctxs[g][tt] = cv;
    float yp = cv * fcwl[tt];
#pragma unroll
    for (int off = 32; off > 0; off >>= 1) yp += __shfl_xor(yp, off);
    if (lane == 0) redA[wv] = yp;
    __syncthreads(); // B6
    float yt0 = redA[0] + redA[1] + redA[2] + redA[3] + fmaf(yh0[s], fcwy, fcb0);
    float yt1 = redA[4] + redA[5] + redA[6] + redA[7] + fmaf(yh1[s], fcwy, fcb0);

    // ---- gates: each thread owns k0=2*tid, k0+1 for both g ----
    const int k0 = tid * 2;
    float wi0 = Wihl[k0], wi1 = Wihl[k0 + 1];
    float bb0 = bl[k0], bb1 = bl[k0 + 1];
    float g00 = fmaf(yt0, wi0, bb0);
    float g01 = fmaf(yt0, wi1, bb1);
    float g10 = fmaf(yt1, wi0, bb0);
    float g11 = fmaf(yt1, wi1, bb1);
#pragma unroll 4
    for (int j = 0; j < 256; ++j) {
      union { unsigned int u; _Float16 h[2]; } cu;
      cu.u = wgr[j * 512 + tid];
      float wa = (float)cu.h[0], wb = (float)cu.h[1];
      float h0 = hc[0][j], h1 = hc[1][j];
      g00 = fmaf(wa, h0, g00);
      g01 = fmaf(wb, h0, g01);
      g10 = fmaf(wa, h1, g10);
      g11 = fmaf(wb, h1, g11);
    }
    gatesS[0][k0] = g00; gatesS[0][k0 + 1] = g01;
    gatesS[1][k0] = g10; gatesS[1][k0 + 1] = g11;
    __syncthreads(); // B7

    // ---- LSTM pointwise ----
    {
      float gi = gatesS[g][tt], gf = gatesS[g][256 + tt],
            gc = gatesS[g][512 + tt], go = gatesS[g][768 + tt];
      float iv = sigmoidf_(gi), fv = sigmoidf_(gf), gv = tanhf_(gc), ov = sigmoidf_(go);
      float cold = hc[g][256 + tt];
      float cn = fmaf(fv, cold, iv * gv);
      float hn = ov * tanhf_(cn);
      hc[g][tt] = hn;
      hc[g][256 + tt] = cn;
    }
    __syncthreads(); // B8
  }

  // ---- epilogue: out[b,o] = [h|ctx] . fcf_w[o] + fcf_b[o] ----
  {
    float hval = hc[g][tt], cval = ctxs[g][tt];
    float p0 = hval * fcfw[tt] + cval * fcfw[256 + tt];
    float p1 = hval * fcfw[512 + tt] + cval * fcfw[768 + tt];
#pragma unroll
    for (int off = 32; off > 0; off >>= 1) {
      p0 += __shfl_xor(p0, off);
      p1 += __shfl_xor(p1, off);
    }
    if (lane == 0) { redA[wv] = p0; redB[wv] = p1; }
    __syncthreads();
    if (tid < 4) {
      int g2 = tid >> 1, o = tid & 1;
      const float* r = (o == 0) ? redA : redB;
      float v = fcfb[o] + r[g2 * 4 + 0] + r[g2 * 4 + 1] + r[g2 * 4 + 2] + r[g2 * 4 + 3];
      out[(b0 + g2) * 2 + o] = v;
    }
  }
}

extern "C" void kernel_launch(void* const* d_in, const int* in_sizes, int n_in,
                              void* d_out, int out_size, void* d_ws, size_t ws_size,
                              hipStream_t stream) {
  (void)in_sizes; (void)n_in; (void)out_size; (void)ws_size;
  const float* x    = (const float*)d_in[0];
  const float* yh   = (const float*)d_in[1];
  const float* w1   = (const float*)d_in[2];
  const float* b1   = (const float*)d_in[3];
  const float* w2   = (const float*)d_in[4];
  /* d_in[5] attn_b2: softmax-invariant, unused */
  const float* Wih  = (const float*)d_in[6];
  const float* Whh  = (const float*)d_in[7];
  const float* bih  = (const float*)d_in[8];
  const float* bhh  = (const float*)d_in[9];
  const float* fcw  = (const float*)d_in[10];
  const float* fcb  = (const float*)d_in[11];
  const float* fcfw = (const float*)d_in[12];
  const float* fcfb = (const float*)d_in[13];
  float* out = (float*)d_out;

  char* ws = (char*)d_ws;
  _Float16* Ph   = (_Float16*)(ws);                      // 67108864 B
  _Float16* xh   = (_Float16*)(ws + (size_t)67108864);   // 67108864 B
  float*    wT   = (float*)   (ws + (size_t)134217728);  // 262144 B
  _Float16* w1hc = (_Float16*)(ws + (size_t)134479872);  // 262144 B
  _Float16* whhT = (_Float16*)(ws + (size_t)134742016);  // 524288 B
  // total workspace: 135266304 B (~129 MB)

  k_prep_wT  <<<256,   256, 0, stream>>>(w1, wT);
  k_prep_xh  <<<32768, 256, 0, stream>>>(x, xh);
  k_prep_w1hc<<<512,   256, 0, stream>>>(w1, w1hc);
  k_prep_whhT<<<1024,  256, 0, stream>>>(Whh, whhT);
  k_encp     <<<8192,  256, 0, stream>>>(x, wT, b1, Ph);
  k_scan     <<<256,   512, 0, stream>>>(Ph, xh, w1hc, whhT, yh, w2, Wih, bih, bhh,
                                         fcw, fcb, fcfw, fcfb, out);
}

// Round 2
// 7869.229 us; speedup vs baseline: 1.7682x; 1.7682x over previous
//
#include <hip/hip_runtime.h>
#include <cstdint>
#include <cstddef>

// Decoder (DA-RNN): B=512, T=256, E=D=256.
// Round 2: (1) y_tilde via precomputed xf[t]=x[t,:]&middot;fcw collapses the per-step
// context sweep (16 GB saved); (2) coalesced layouts for Ph/w1hc/W_hh;
// (3) nontemporal loads on the Ph stream to keep weights L2-resident;
// (4) v_dot2_f32_f16 for q/gates GEMVs; 5 barriers/step (was 8).

typedef _Float16 half8 __attribute__((ext_vector_type(8)));
typedef _Float16 half4v __attribute__((ext_vector_type(4)));
typedef _Float16 half2v __attribute__((ext_vector_type(2)));

__device__ __forceinline__ float rcpf_(float x) { return __builtin_amdgcn_rcpf(x); }
__device__ __forceinline__ float sigmoidf_(float x) { return rcpf_(1.f + __expf(-x)); }
__device__ __forceinline__ float tanhf_(float x) { return 1.f - 2.f * rcpf_(1.f + __expf(2.f * x)); }

#if defined(__has_builtin)
#if __has_builtin(__builtin_amdgcn_fdot2)
#define HAS_FDOT2 1
#endif
#endif
#ifndef HAS_FDOT2
#define HAS_FDOT2 0
#endif

__device__ __forceinline__ float fdot2_(half2v a, half2v b, float c) {
#if HAS_FDOT2
  return __builtin_amdgcn_fdot2(a, b, c, false);
#else
  return fmaf((float)a[0], (float)b[0], fmaf((float)a[1], (float)b[1], c));
#endif
}

// ---------------- prep kernels ----------------

// wT[e*256+f] = attn_w1[f*768 + 512 + e]   (transposed w1_enc, fp32)
__global__ void k_prep_wT(const float* __restrict__ w1, float* __restrict__ wT) {
  int id = blockIdx.x * 256 + threadIdx.x;
  int e = id >> 8, f = id & 255;
  wT[id] = w1[f * 768 + 512 + e];
}

// x -> fp16 (4 elems/thread), layout unchanged [b][t][e]
__global__ void k_prep_xh(const float* __restrict__ x, _Float16* __restrict__ xh) {
  int id = blockIdx.x * 256 + threadIdx.x;
  float4 v = reinterpret_cast<const float4*>(x)[id];
  half4v h;
  h[0] = (_Float16)v.x; h[1] = (_Float16)v.y; h[2] = (_Float16)v.z; h[3] = (_Float16)v.w;
  reinterpret_cast<half4v*>(xh)[id] = h;
}

// w1hcP[(c*512 + e*2 + jh)*8 + m] = w1[e*768 + jh*256 + c*8 + m]  (fp16)
// (thread tid=e*2+jh in k_scan reads chunk c as contiguous 16B)
__global__ void k_prep_w1hcP(const float* __restrict__ w1, _Float16* __restrict__ o) {
  int id = blockIdx.x * 256 + threadIdx.x;  // 131072 total
  int m = id & 7, lane = (id >> 3) & 511, c = id >> 12;
  int e = lane >> 1, jh = lane & 1;
  o[id] = (_Float16)w1[e * 768 + jh * 256 + c * 8 + m];
}

// whhT3[(jp*1024 + k)*2 + r] = W_hh[k*256 + 2*jp + r]  (fp16, j-pair packed)
__global__ void k_prep_whhT3(const float* __restrict__ whh, _Float16* __restrict__ o) {
  int id = blockIdx.x * 256 + threadIdx.x;  // 262144 total
  int r = id & 1, k = (id >> 1) & 1023, jp = id >> 11;
  o[id] = (_Float16)whh[k * 256 + 2 * jp + r];
}

// xf[b*256+t] = sum_e x[b,t,e] * fcw[e]   (fp32)
__global__ __launch_bounds__(256) void k_xf(const float* __restrict__ x,
                                            const float* __restrict__ fcw,
                                            float* __restrict__ xf) {
  __shared__ float xl[16][256];
  __shared__ float fw[256];
  __shared__ float part[16][17];
  const int tid = threadIdx.x;
  const int m0 = blockIdx.x * 16;
  fw[tid] = fcw[tid];
#pragma unroll
  for (int r = 0; r < 16; ++r) xl[r][tid] = x[(size_t)(m0 + r) * 256 + tid];
  __syncthreads();
  int r = tid >> 4, p = tid & 15;
  float s = 0.f;
#pragma unroll
  for (int u = 0; u < 16; ++u) s = fmaf(xl[r][p * 16 + u], fw[p * 16 + u], s);
  part[r][p] = s;
  __syncthreads();
  if (tid < 16) {
    float t = 0.f;
#pragma unroll
    for (int p2 = 0; p2 < 16; ++p2) t += part[tid][p2];
    xf[m0 + tid] = t;
  }
}

// enc_proj GEMM + bias, store P=exp(2*encp) fp16 in layout [b][e/8][t][e%8]
__global__ __launch_bounds__(256) void k_encp(const float* __restrict__ x,
                                              const float* __restrict__ wT,
                                              const float* __restrict__ b1,
                                              _Float16* __restrict__ Ph2) {
  __shared__ __align__(16) float xl[16][256];
  const int tid = threadIdx.x;
  const int m0 = blockIdx.x * 16;
#pragma unroll
  for (int r = 0; r < 16; ++r) xl[r][tid] = x[(size_t)(m0 + r) * 256 + tid];
  __syncthreads();
  float acc[16];
#pragma unroll
  for (int r = 0; r < 16; ++r) acc[r] = 0.f;
  for (int e = 0; e < 256; e += 4) {
    float w0 = wT[(e + 0) * 256 + tid];
    float w1_ = wT[(e + 1) * 256 + tid];
    float w2_ = wT[(e + 2) * 256 + tid];
    float w3_ = wT[(e + 3) * 256 + tid];
#pragma unroll
    for (int r = 0; r < 16; ++r) {
      float4 xv = *reinterpret_cast<const float4*>(&xl[r][e]);
      acc[r] = fmaf(xv.x, w0, acc[r]);
      acc[r] = fmaf(xv.y, w1_, acc[r]);
      acc[r] = fmaf(xv.z, w2_, acc[r]);
      acc[r] = fmaf(xv.w, w3_, acc[r]);
    }
  }
  float bb = b1[tid];
  const int e = tid;
#pragma unroll
  for (int r = 0; r < 16; ++r) {
    int m = m0 + r, b = m >> 8, t = m & 255;
    float p = __expf(2.f * (acc[r] + bb));
    Ph2[((size_t)(b * 32 + (e >> 3)) * 256 + t) * 8 + (e & 7)] = (_Float16)p;
  }
}

// ---------------- the scan ----------------
// grid 256 x 512 threads; wg owns 2 batch rows (g=0/1); 256 steps.
__global__ __launch_bounds__(512, 2) void k_scan(
    const _Float16* __restrict__ Ph2, const _Float16* __restrict__ xh,
    const _Float16* __restrict__ w1hcP, const _Float16* __restrict__ whhT3,
    const float* __restrict__ xf, const float* __restrict__ y_hist,
    const float* __restrict__ w2g, const float* __restrict__ Wih,
    const float* __restrict__ bih, const float* __restrict__ bhh,
    const float* __restrict__ fcw, const float* __restrict__ fcb,
    const float* __restrict__ fcfw, const float* __restrict__ fcfb,
    float* __restrict__ out) {
  __shared__ __align__(16) float hc[2][512];        // fp32 [g][ h | c ]
  __shared__ __align__(16) _Float16 hcH[2][512];    // fp16 mirror for dot2
  __shared__ __align__(16) float qpart[2][2][256];  // [g][jh][e]
  __shared__ __align__(16) float Qs[2][256];        // exp(2q)
  __shared__ __align__(16) float ealpha[2][256];
  __shared__ __align__(16) float gpart[4][2][1024]; // [jq][g][k]
  __shared__ __align__(16) float cpart[2][8][256];  // final ctx only
  __shared__ __align__(16) float w2l[256];
  __shared__ __align__(16) float Wihl[1024];
  __shared__ __align__(16) float bl[1024];
  __shared__ __align__(16) float xfL[2][256];
  __shared__ float redA[8], redB[8];

  const int tid = threadIdx.x;
  const int g = tid >> 8;
  const int tt = tid & 255;
  const int wv = tid >> 6;
  const int lane = tid & 63;
  const int b0 = blockIdx.x * 2;

  // ---- init ----
  ((float*)hc)[tid] = 0.f;
  ((float*)hc)[tid + 512] = 0.f;
  {
    _Float16 z = (_Float16)0.f;
    ((_Float16*)hcH)[tid] = z;
    ((_Float16*)hcH)[tid + 512] = z;
  }
  if (g == 0) w2l[tt] = w2g[tt];
  Wihl[tid] = Wih[tid];
  Wihl[tid + 512] = Wih[tid + 512];
  bl[tid] = bih[tid] + bhh[tid];
  bl[tid + 512] = bih[tid + 512] + bhh[tid + 512];
  xfL[g][tt] = xf[(size_t)(b0 + g) * 256 + tt];
  __syncthreads();
  float w2sum = 0.f;
  for (int e2 = 0; e2 < 256; ++e2) w2sum += w2l[e2];
  const float fcb0 = fcb[0];
  const float fcwy = fcw[256];

  // per-thread pointers
  const half8* wq = reinterpret_cast<const half8*>(w1hcP) + tid;  // chunk c: wq[c*512]
  const int jh = tid & 1, eQ = tid >> 1;
  const half8* prow = reinterpret_cast<const half8*>(Ph2) + ((size_t)(b0 + g) * 32) * 256 + tt;
  const int ks = tid & 127, jq = tid >> 7, k0 = (tid & 127) * 8;
  const half8* wgp = reinterpret_cast<const half8*>(whhT3) + ks * 2;
  const float* yh0 = y_hist + (size_t)b0 * 256;
  const float* yh1 = y_hist + (size_t)(b0 + 1) * 256;

  float rs0 = 0.f;  // kept for final context (value from last step)

#pragma unroll 1
  for (int s = 0; s < 256; ++s) {
    // ---- q[e] = hc . w1_hc[e,:], split over j-halves, both g ----
    float a0 = 0.f, a1 = 0.f;
    {
      const half2v* h0 = reinterpret_cast<const half2v*>(&hcH[0][jh * 256]);
      const half2v* h1 = reinterpret_cast<const half2v*>(&hcH[1][jh * 256]);
#pragma unroll 8
      for (int c = 0; c < 32; ++c) {
        half8 wv8 = wq[c * 512];
#pragma unroll
        for (int p = 0; p < 4; ++p) {
          half2v wp2 = __builtin_shufflevector(wv8, wv8, 0, 1);
          if (p == 1) wp2 = __builtin_shufflevector(wv8, wv8, 2, 3);
          if (p == 2) wp2 = __builtin_shufflevector(wv8, wv8, 4, 5);
          if (p == 3) wp2 = __builtin_shufflevector(wv8, wv8, 6, 7);
          a0 = fdot2_(wp2, h0[c * 4 + p], a0);
          a1 = fdot2_(wp2, h1[c * 4 + p], a1);
        }
      }
    }
    qpart[0][jh][eQ] = a0;
    qpart[1][jh][eQ] = a1;
    __syncthreads();  // B1
    Qs[g][tt] = __expf(2.f * (qpart[g][0][tt] + qpart[g][1][tt]));
    __syncthreads();  // B2

    // ---- scores over t: sc = w2sum - 2*sum_e w2[e]/(P*Q+1) ----
    float sacc = 0.f;
    {
      const float4* q4 = reinterpret_cast<const float4*>(&Qs[g][0]);
      const float4* w4 = reinterpret_cast<const float4*>(&w2l[0]);
#pragma unroll 8
      for (int c = 0; c < 32; ++c) {
        half8 pv = __builtin_nontemporal_load(prow + c * 256);
        float4 qa = q4[2 * c], qb = q4[2 * c + 1];
        float4 wa = w4[2 * c], wb = w4[2 * c + 1];
        sacc = fmaf(wa.x, rcpf_(fmaf((float)pv[0], qa.x, 1.f)), sacc);
        sacc = fmaf(wa.y, rcpf_(fmaf((float)pv[1], qa.y, 1.f)), sacc);
        sacc = fmaf(wa.z, rcpf_(fmaf((float)pv[2], qa.z, 1.f)), sacc);
        sacc = fmaf(wa.w, rcpf_(fmaf((float)pv[3], qa.w, 1.f)), sacc);
        sacc = fmaf(wb.x, rcpf_(fmaf((float)pv[4], qb.x, 1.f)), sacc);
        sacc = fmaf(wb.y, rcpf_(fmaf((float)pv[5], qb.y, 1.f)), sacc);
        sacc = fmaf(wb.z, rcpf_(fmaf((float)pv[6], qb.z, 1.f)), sacc);
        sacc = fmaf(wb.w, rcpf_(fmaf((float)pv[7], qb.w, 1.f)), sacc);
      }
    }
    float sc = w2sum - 2.f * sacc;
    float ea = __expf(sc);  // no max-sub: |sc| <= ~21, fp32-safe
    ealpha[g][tt] = ea;
    float ef = ea * xfL[g][tt];
    float es = ea;
#pragma unroll
    for (int off = 32; off > 0; off >>= 1) {
      es += __shfl_xor(es, off);
      ef += __shfl_xor(ef, off);
    }
    if (lane == 0) { redA[wv] = es; redB[wv] = ef; }
    __syncthreads();  // B3
    float es0 = redA[0] + redA[1] + redA[2] + redA[3];
    float es1 = redA[4] + redA[5] + redA[6] + redA[7];
    float ef0 = redB[0] + redB[1] + redB[2] + redB[3];
    float ef1 = redB[4] + redB[5] + redB[6] + redB[7];
    float yt0 = ef0 * rcpf_(es0) + fmaf(yh0[s], fcwy, fcb0);
    float yt1 = ef1 * rcpf_(es1) + fmaf(yh1[s], fcwy, fcb0);
    rs0 = rcpf_(g == 0 ? es0 : es1);

    // ---- gates: thread (ks,jq) -> outputs k0..k0+7 over j in [jq*64,jq*64+64) ----
    float acc0[8], acc1[8];
#pragma unroll
    for (int m = 0; m < 8; ++m) { acc0[m] = 0.f; acc1[m] = 0.f; }
    {
      const unsigned int* hu0 = reinterpret_cast<const unsigned int*>(&hcH[0][0]);
      const unsigned int* hu1 = reinterpret_cast<const unsigned int*>(&hcH[1][0]);
      const int jp0 = jq * 32;
#pragma unroll 8
      for (int u = 0; u < 32; ++u) {
        int jp = jp0 + u;
        half8 wa = wgp[jp * 256];
        half8 wb = wgp[jp * 256 + 1];
        unsigned int u0 = hu0[jp], u1 = hu1[jp];
        half2v h0 = __builtin_bit_cast(half2v, u0);
        half2v h1 = __builtin_bit_cast(half2v, u1);
        half2v p0 = __builtin_shufflevector(wa, wa, 0, 1);
        half2v p1 = __builtin_shufflevector(wa, wa, 2, 3);
        half2v p2 = __builtin_shufflevector(wa, wa, 4, 5);
        half2v p3 = __builtin_shufflevector(wa, wa, 6, 7);
        half2v p4 = __builtin_shufflevector(wb, wb, 0, 1);
        half2v p5 = __builtin_shufflevector(wb, wb, 2, 3);
        half2v p6 = __builtin_shufflevector(wb, wb, 4, 5);
        half2v p7 = __builtin_shufflevector(wb, wb, 6, 7);
        acc0[0] = fdot2_(p0, h0, acc0[0]); acc1[0] = fdot2_(p0, h1, acc1[0]);
        acc0[1] = fdot2_(p1, h0, acc0[1]); acc1[1] = fdot2_(p1, h1, acc1[1]);
        acc0[2] = fdot2_(p2, h0, acc0[2]); acc1[2] = fdot2_(p2, h1, acc1[2]);
        acc0[3] = fdot2_(p3, h0, acc0[3]); acc1[3] = fdot2_(p3, h1, acc1[3]);
        acc0[4] = fdot2_(p4, h0, acc0[4]); acc1[4] = fdot2_(p4, h1, acc1[4]);
        acc0[5] = fdot2_(p5, h0, acc0[5]); acc1[5] = fdot2_(p5, h1, acc1[5]);
        acc0[6] = fdot2_(p6, h0, acc0[6]); acc1[6] = fdot2_(p6, h1, acc1[6]);
        acc0[7] = fdot2_(p7, h0, acc0[7]); acc1[7] = fdot2_(p7, h1, acc1[7]);
      }
    }
    *reinterpret_cast<float4*>(&gpart[jq][0][k0]) = *reinterpret_cast<float4*>(&acc0[0]);
    *reinterpret_cast<float4*>(&gpart[jq][0][k0 + 4]) = *reinterpret_cast<float4*>(&acc0[4]);
    *reinterpret_cast<float4*>(&gpart[jq][1][k0]) = *reinterpret_cast<float4*>(&acc1[0]);
    *reinterpret_cast<float4*>(&gpart[jq][1][k0 + 4]) = *reinterpret_cast<float4*>(&acc1[4]);
    __syncthreads();  // B4

    // ---- LSTM pointwise: thread (g,tt) ----
    {
      float yt = (g == 0) ? yt0 : yt1;
      float gi = fmaf(yt, Wihl[tt], bl[tt]);
      float gf = fmaf(yt, Wihl[256 + tt], bl[256 + tt]);
      float gc = fmaf(yt, Wihl[512 + tt], bl[512 + tt]);
      float go = fmaf(yt, Wihl[768 + tt], bl[768 + tt]);
#pragma unroll
      for (int q2 = 0; q2 < 4; ++q2) {
        gi += gpart[q2][g][tt];
        gf += gpart[q2][g][256 + tt];
        gc += gpart[q2][g][512 + tt];
        go += gpart[q2][g][768 + tt];
      }
      float iv = sigmoidf_(gi), fv = sigmoidf_(gf), gv = tanhf_(gc), ov = sigmoidf_(go);
      float cold = hc[g][256 + tt];
      float cn = fmaf(fv, cold, iv * gv);
      float hn = ov * tanhf_(cn);
      hc[g][tt] = hn;
      hc[g][256 + tt] = cn;
      hcH[g][tt] = (_Float16)hn;
      hcH[g][256 + tt] = (_Float16)cn;
    }
    __syncthreads();  // B5
  }

  // ---- final context (uses ealpha/rs0 from step 255) ----
  const int t8 = tt >> 5, l5 = tt & 31;
  {
    const half8* xrow = reinterpret_cast<const half8*>(xh + ((size_t)(b0 + g) * 256 + t8 * 32) * 256);
    float ac[8];
#pragma unroll
    for (int m = 0; m < 8; ++m) ac[m] = 0.f;
#pragma unroll 4
    for (int it = 0; it < 32; ++it) {
      float al = ealpha[g][t8 * 32 + it];
      half8 xv = xrow[it * 32 + l5];
#pragma unroll
      for (int m = 0; m < 8; ++m) ac[m] = fmaf(al, (float)xv[m], ac[m]);
    }
    *reinterpret_cast<float4*>(&cpart[g][t8][l5 * 8]) = *reinterpret_cast<float4*>(&ac[0]);
    *reinterpret_cast<float4*>(&cpart[g][t8][l5 * 8 + 4]) = *reinterpret_cast<float4*>(&ac[4]);
  }
  __syncthreads();
  float cv = 0.f;
#pragma unroll
  for (int u = 0; u < 8; ++u) cv += cpart[g][u][tt];
  cv *= rs0;

  // ---- epilogue: out[b,o] = [h|ctx].fcf_w[o] + fcf_b[o] ----
  {
    float hval = hc[g][tt];
    float p0 = hval * fcfw[tt] + cv * fcfw[256 + tt];
    float p1 = hval * fcfw[512 + tt] + cv * fcfw[768 + tt];
#pragma unroll
    for (int off = 32; off > 0; off >>= 1) {
      p0 += __shfl_xor(p0, off);
      p1 += __shfl_xor(p1, off);
    }
    __syncthreads();  // protect redA/redB reuse
    if (lane == 0) { redA[wv] = p0; redB[wv] = p1; }
    __syncthreads();
    if (tid < 4) {
      int g2 = tid >> 1, o = tid & 1;
      const float* r = (o == 0) ? redA : redB;
      float v = fcfb[o] + r[g2 * 4 + 0] + r[g2 * 4 + 1] + r[g2 * 4 + 2] + r[g2 * 4 + 3];
      out[(b0 + g2) * 2 + o] = v;
    }
  }
}

extern "C" void kernel_launch(void* const* d_in, const int* in_sizes, int n_in,
                              void* d_out, int out_size, void* d_ws, size_t ws_size,
                              hipStream_t stream) {
  (void)in_sizes; (void)n_in; (void)out_size; (void)ws_size;
  const float* x    = (const float*)d_in[0];
  const float* yh   = (const float*)d_in[1];
  const float* w1   = (const float*)d_in[2];
  const float* b1   = (const float*)d_in[3];
  const float* w2   = (const float*)d_in[4];
  /* d_in[5] attn_b2: softmax-invariant, unused */
  const float* Wih  = (const float*)d_in[6];
  const float* Whh  = (const float*)d_in[7];
  const float* bih  = (const float*)d_in[8];
  const float* bhh  = (const float*)d_in[9];
  const float* fcw  = (const float*)d_in[10];
  const float* fcb  = (const float*)d_in[11];
  const float* fcfw = (const float*)d_in[12];
  const float* fcfb = (const float*)d_in[13];
  float* out = (float*)d_out;

  char* ws = (char*)d_ws;
  _Float16* Ph2   = (_Float16*)(ws);                      // 67108864 B
  _Float16* xh    = (_Float16*)(ws + (size_t)67108864);   // 67108864 B
  float*    wT    = (float*)   (ws + (size_t)134217728);  // 262144 B
  _Float16* w1hcP = (_Float16*)(ws + (size_t)134479872);  // 262144 B
  _Float16* whhT3 = (_Float16*)(ws + (size_t)134742016);  // 524288 B
  float*    xf    = (float*)   (ws + (size_t)135266304);  // 524288 B
  // total: 135790592 B (~129.5 MB)

  k_prep_wT   <<<256,   256, 0, stream>>>(w1, wT);
  k_prep_xh   <<<32768, 256, 0, stream>>>(x, xh);
  k_prep_w1hcP<<<512,   256, 0, stream>>>(w1, w1hcP);
  k_prep_whhT3<<<1024,  256, 0, stream>>>(Whh, whhT3);
  k_xf        <<<8192,  256, 0, stream>>>(x, fcw, xf);
  k_encp      <<<8192,  256, 0, stream>>>(x, wT, b1, Ph2);
  k_scan      <<<256,   512, 0, stream>>>(Ph2, xh, w1hcP, whhT3, xf, yh, w2, Wih,
                                          bih, bhh, fcw, fcb, fcfw, fcfb, out);
}